// Round 13
// baseline (209.985 us; speedup 1.0000x reference)
//
#include <hip/hip_runtime.h>
#include <math.h>

#define B_ 32
#define NODES_ 512
#define IN_ 256
#define OUT_ 128
#define CAPS_ 16
#define KW_ 5
#define M_ (B_*NODES_)            // 16384
#define N_ (KW_*OUT_)             // 640
#define NCH 32                    // node chunks of 16

typedef __attribute__((ext_vector_type(8))) short short8;
typedef __attribute__((ext_vector_type(4))) float f32x4;

// ---- workspace layout (bytes) ---- (round-5 proven: 51,642,368 total)
#define Y_BOFF   0
#define L_BOFF   41943040
#define V_BOFF   42991616
#define SP_BOFF  43253760
#define BT_SZ    (N_*IN_*2)       // 327,680 bytes each

#define APAD 84                   // alpha row pad

__device__ __forceinline__ float b2f(unsigned short u) {
  union { unsigned int i; float f; } c; c.i = ((unsigned int)u) << 16; return c.f;
}
__device__ __forceinline__ unsigned short f2b(float f) {
  union { float f; unsigned int i; } c; c.f = f;
  unsigned int u = c.i;
  u += 0x7fffu + ((u >> 16) & 1u);
  return (unsigned short)(u >> 16);
}
__device__ __forceinline__ void async_load16(const void* g, void* l) {
  __builtin_amdgcn_global_load_lds(
      (const __attribute__((address_space(1))) unsigned int*)g,
      (__attribute__((address_space(3))) unsigned int*)l, 16, 0, 0);
}

// wait until <=NN vmem ops outstanding, then block barrier (no full drain).
// sched_barrier(0) fences compiler motion around the asm (rule #18).
#define WAIT_PLANE(NN) do {                                        \
    asm volatile("s_waitcnt vmcnt(" #NN ")" ::: "memory");         \
    __builtin_amdgcn_sched_barrier(0);                             \
    __builtin_amdgcn_s_barrier();                                  \
    __builtin_amdgcn_sched_barrier(0);                             \
  } while (0)

// ============================================================
// conv_w: split W into K-MAJOR bf16 hi/lo panels.
// ============================================================
__global__ __launch_bounds__(256) void conv_w(const float* __restrict__ W,
                                              unsigned short* __restrict__ bThi,
                                              unsigned short* __restrict__ bTlo) {
  int n = blockIdx.x;           // 0..639
  int i = threadIdx.x;          // 0..255
  int k = n >> 7, o = n & 127;
  float v = W[((size_t)k*IN_ + i)*OUT_ + o];
  unsigned short h = f2b(v);
  size_t dst = ((size_t)(i >> 3)*N_ + n)*8 + (i & 7);
  bThi[dst] = h;
  bTlo[dst] = f2b(v - b2f(h));
}

// ============================================================
// gemm_fn (R10-proven, ~11us): FULL-N blocks, coalesced reg-staged A,
// flat gload_lds B panels, split-bf16 3-pass MFMA.
// ============================================================
__global__ __launch_bounds__(512) void gemm_fn(const float* __restrict__ x,
                                               const unsigned short* __restrict__ bThi,
                                               const unsigned short* __restrict__ bTlo,
                                               float* __restrict__ y) {
  __shared__ float A_lds[8*64*4];      //  8 KB [cg][row][4f]
  __shared__ short Bh_lds[4*640*8];    // 40 KB [kg][n][8]
  __shared__ short Bl_lds[4*640*8];    // 40 KB
  const int t    = threadIdx.x;
  const int w    = t >> 6;
  const int lane = t & 63;
  const int lrow = lane & 15;
  const int lk   = lane >> 4;
  const int m0   = blockIdx.x * 64;
  const int wn0  = w * 80;
  const int arow = t >> 3;
  const int ac4  = t & 7;

  f32x4 acc[4][5];
  #pragma unroll
  for (int i=0;i<4;++i)
    #pragma unroll
    for (int j=0;j<5;++j) acc[i][j] = (f32x4){0.f,0.f,0.f,0.f};

  for (int kbi = 0; kbi < 8; ++kbi) {
    const int kb = kbi*32;
    const unsigned short* bh_src = bThi + (size_t)kbi*4*N_*8;
    const unsigned short* bl_src = bTlo + (size_t)kbi*4*N_*8;
    #pragma unroll
    for (int q=0; q<5; ++q) {
      int db = q*512 + w*64;
      async_load16(bh_src + (size_t)(db + lane)*8, &Bh_lds[db*8]);
      async_load16(bl_src + (size_t)(db + lane)*8, &Bl_lds[db*8]);
    }
    {
      float4 av = *(const float4*)(x + (size_t)(m0 + arow)*IN_ + kb + ac4*4);
      *(float4*)&A_lds[((ac4*64) + arow)*4] = av;
    }
    __syncthreads();

    short8 ah[4], al[4];
    #pragma unroll
    for (int mi=0; mi<4; ++mi) {
      int row = mi*16 + lrow;
      f32x4 a0 = *(const f32x4*)&A_lds[((2*lk  )*64 + row)*4];
      f32x4 a1 = *(const f32x4*)&A_lds[((2*lk+1)*64 + row)*4];
      #pragma unroll
      for (int j=0; j<8; ++j) {
        float f = (j < 4) ? a0[j] : a1[j-4];
        unsigned short h = f2b(f);
        ah[mi][j] = (short)h;
        al[mi][j] = (short)f2b(f - b2f(h));
      }
    }
    #pragma unroll
    for (int ni=0; ni<5; ++ni) {
      int nb = wn0 + ni*16 + lrow;
      short8 bh = *(const short8*)&Bh_lds[(lk*N_ + nb)*8];
      short8 bl = *(const short8*)&Bl_lds[(lk*N_ + nb)*8];
      #pragma unroll
      for (int mi=0; mi<4; ++mi) {
        acc[mi][ni] = __builtin_amdgcn_mfma_f32_16x16x32_bf16(bh, ah[mi], acc[mi][ni], 0, 0, 0);
        acc[mi][ni] = __builtin_amdgcn_mfma_f32_16x16x32_bf16(bh, al[mi], acc[mi][ni], 0, 0, 0);
        acc[mi][ni] = __builtin_amdgcn_mfma_f32_16x16x32_bf16(bl, ah[mi], acc[mi][ni], 0, 0, 0);
      }
    }
    __syncthreads();
  }

  #pragma unroll
  for (int mi=0; mi<4; ++mi) {
    int m = m0 + mi*16 + lrow;
    #pragma unroll
    for (int ni=0; ni<5; ++ni) {
      int nb = wn0 + ni*16 + lk*4;
      float4 o = {acc[mi][ni][0], acc[mi][ni][1], acc[mi][ni][2], acc[mi][ni][3]};
      *(float4*)(y + (size_t)m*N_ + nb) = o;
    }
  }
}

// ============================================================
// route_pipe: one routing sweep, 16-node chunk per block (256 thr).
// y staged as 5 k-planes (8 KB each) via global_load_lds issued
// plane-major; consumed behind COUNTED vmcnt waits (never 0 until
// last plane) -> planes 1-4 latency hides under plane 0-3 compute.
// mode 1: phase1 pipelined per plane; mode 0: phase2 pipelined.
// Softmax = 16-lane shfl_xor (no serial t<16 section).
// ============================================================
__global__ __launch_bounds__(256) void route_pipe(const float* __restrict__ y,
                                                  const float* __restrict__ alpha,
                                                  const float* __restrict__ contrib,
                                                  float* __restrict__ logits,
                                                  const float* __restrict__ vin,
                                                  float* __restrict__ s_part,
                                                  int mode) {
  __shared__ __align__(16) float sh_y[5*16*128];    // 40 KB [k][node][o]
  __shared__ __align__(16) float sh_v[16*132];      //  8.4 KB [cap][o]
  __shared__ __align__(16) float sh_alpha[16*APAD]; //  5.4 KB [node][cap*5+k]
  __shared__ float sh_logit[16][16];                // cw (phase 2)

  const int t  = threadIdx.x;
  const int ch = blockIdx.x;   // 0..31
  const int b  = blockIdx.y;   // 0..31
  const int n0 = ch*16;
  const int node = t >> 4, cap = t & 15;  // phase-1 / logits mapping

  // ---- A: stage alpha (+v, logits->reg in mode 1) BEFORE y issues ----
  const float* abase = alpha + (size_t)n0*CAPS_*KW_;
  for (int i = t; i < 320; i += 256) {
    float4 av = *(const float4*)(abase + i*4);
    int flat = i*4;
    int nd   = flat / 80;
    int rem  = flat - nd*80;
    *(float4*)&sh_alpha[nd*APAD + rem] = av;
  }
  float lreg = 0.f;
  if (mode >= 1) {
    const float* vbase = vin + (size_t)b*CAPS_*OUT_;
    #pragma unroll
    for (int q=0; q<2; ++q) {
      int flat = (t + q*256)*4;
      int c = flat >> 7, o = flat & 127;
      float4 vv = *(const float4*)(vbase + flat);
      *(float4*)&sh_v[c*132 + o] = vv;
    }
    lreg = logits[((size_t)b*CAPS_ + cap)*NODES_ + n0 + node];
  }
  // drain ALL pre-stage vmem + LDS writes so plane vmcnt counts are exact
  asm volatile("s_waitcnt vmcnt(0) lgkmcnt(0)" ::: "memory");
  __builtin_amdgcn_sched_barrier(0);

  // ---- B: issue y plane loads, plane-major (2 chunks/thread/plane) ----
  const float* ybase = y + (size_t)(b*NODES_ + n0)*N_;
  #pragma unroll
  for (int k=0; k<5; ++k) {
    #pragma unroll
    for (int q=0; q<2; ++q) {
      int d0 = q*256 + (t & ~63);            // wave-uniform chunk base
      int d  = d0 + (t & 63);
      int nd = d >> 5, c4 = d & 31;
      async_load16(ybase + (size_t)nd*N_ + k*128 + c4*4,
                   &sh_y[k*2048 + d0*4]);
    }
  }

  if (mode >= 1) {
    // ---- phase 1 pipelined over planes ----
    const float* vb = &sh_v[cap*132];
    const int ro = (node & 3)*2;             // bank rotation (quads)
    float accd = 0.f;
#define P1K(KK, NN) do {                                             \
    WAIT_PLANE(NN);                                                  \
    const float* yk = &sh_y[(KK*16 + node)*128];                     \
    float dot = 0.f;                                                 \
    _Pragma("unroll")                                                \
    for (int oi=0; oi<32; ++oi) {                                    \
      int oq = ((oi + ro) & 31)*4;                                   \
      float4 yv = *(const float4*)(yk + oq);                         \
      float4 vv = *(const float4*)(vb + oq);                         \
      dot += yv.x*vv.x + yv.y*vv.y + yv.z*vv.z + yv.w*vv.w;          \
    }                                                                \
    accd += sh_alpha[node*APAD + cap*5 + KK] * dot;                  \
  } while (0)
    P1K(0, 8); P1K(1, 6); P1K(2, 4); P1K(3, 2); P1K(4, 0);
#undef P1K
    float newl = lreg + accd;
    logits[((size_t)b*CAPS_ + cap)*NODES_ + n0 + node] = newl;
    // softmax over caps via 16-lane butterfly (lanes 0-15 = caps of one node)
    float m = newl;
    m = fmaxf(m, __shfl_xor(m, 1, 64));
    m = fmaxf(m, __shfl_xor(m, 2, 64));
    m = fmaxf(m, __shfl_xor(m, 4, 64));
    m = fmaxf(m, __shfl_xor(m, 8, 64));
    float e = __expf(newl - m);
    float ssum = e;
    ssum += __shfl_xor(ssum, 1, 64);
    ssum += __shfl_xor(ssum, 2, 64);
    ssum += __shfl_xor(ssum, 4, 64);
    ssum += __shfl_xor(ssum, 8, 64);
    sh_logit[node][cap] = e / ssum;
    asm volatile("s_waitcnt lgkmcnt(0)" ::: "memory");
    __builtin_amdgcn_sched_barrier(0);
    __builtin_amdgcn_s_barrier();
    __builtin_amdgcn_sched_barrier(0);

    // ---- phase 2 (all planes resident): c fast -> y broadcast ----
    const int c0 = t & 15;
    const int q0 = t >> 4;                   // o0=q0*4, o1=(q0+16)*4
    float4 acc0 = {0,0,0,0}, acc1 = {0,0,0,0};
    #pragma unroll 4
    for (int nd=0; nd<16; ++nd) {
      float cw = sh_logit[nd][c0];
      #pragma unroll
      for (int k=0; k<5; ++k) {
        float ce = cw * sh_alpha[nd*APAD + c0*5 + k];
        const float* yk = &sh_y[(k*16 + nd)*128];
        float4 y0 = *(const float4*)(yk + q0*4);
        float4 y1 = *(const float4*)(yk + (q0+16)*4);
        acc0.x += ce*y0.x; acc0.y += ce*y0.y; acc0.z += ce*y0.z; acc0.w += ce*y0.w;
        acc1.x += ce*y1.x; acc1.y += ce*y1.y; acc1.z += ce*y1.z; acc1.w += ce*y1.w;
      }
    }
    float* spb = s_part + ((size_t)(b*NCH + ch)*CAPS_ + c0)*OUT_;
    *(float4*)(spb + q0*4)      = acc0;
    *(float4*)(spb + (q0+16)*4) = acc1;
  } else {
    // ---- mode 0: uniform c=1/16; phase 2 pipelined over planes ----
    const int c0 = t & 15;
    const int q0 = t >> 4;
    float4 acc0 = {0,0,0,0}, acc1 = {0,0,0,0};
#define P2K(KK, NN) do {                                             \
    WAIT_PLANE(NN);                                                  \
    _Pragma("unroll 4")                                              \
    for (int nd=0; nd<16; ++nd) {                                    \
      float ce = 0.0625f * sh_alpha[nd*APAD + c0*5 + KK];            \
      const float* yk = &sh_y[(KK*16 + nd)*128];                     \
      float4 y0 = *(const float4*)(yk + q0*4);                       \
      float4 y1 = *(const float4*)(yk + (q0+16)*4);                  \
      acc0.x += ce*y0.x; acc0.y += ce*y0.y; acc0.z += ce*y0.z; acc0.w += ce*y0.w; \
      acc1.x += ce*y1.x; acc1.y += ce*y1.y; acc1.z += ce*y1.z; acc1.w += ce*y1.w; \
    }                                                                \
  } while (0)
    P2K(0, 8); P2K(1, 6); P2K(2, 4); P2K(3, 2); P2K(4, 0);
#undef P2K
    float* spb = s_part + ((size_t)(b*NCH + ch)*CAPS_ + c0)*OUT_;
    *(float4*)(spb + q0*4)      = acc0;
    *(float4*)(spb + (q0+16)*4) = acc1;
    // init logits from contribution (no pending counted waits now)
    logits[((size_t)b*CAPS_ + cap)*NODES_ + n0 + node] =
        contrib[(size_t)b*NODES_ + n0 + node];
  }
}

// ============================================================
// squash_k: reduce s_part over chunks, squash, write v (or out)
// ============================================================
__global__ __launch_bounds__(128) void squash_k(const float* __restrict__ s_part,
                                                float* __restrict__ out) {
  const int bc = blockIdx.x;       // b*16+c
  const int o  = threadIdx.x;      // 0..127
  const int b = bc >> 4, c = bc & 15;
  const float* sp = s_part + ((size_t)(b*NCH)*CAPS_ + c)*OUT_ + o;
  float s = 0.f;
  #pragma unroll
  for (int ch=0; ch<NCH; ++ch) s += sp[(size_t)ch*CAPS_*OUT_];
  float ss = s*s;
  #pragma unroll
  for (int off=32; off>0; off>>=1) ss += __shfl_down(ss, off, 64);
  __shared__ float red[2];
  if ((o & 63) == 0) red[o>>6] = ss;
  __syncthreads();
  float sn = red[0] + red[1];
  float scale = (sn/(1.f+sn)) / (sqrtf(sn)+1e-8f);
  out[(size_t)bc*OUT_ + o] = scale*s;
}

// ============================================================
extern "C" void kernel_launch(void* const* d_in, const int* in_sizes, int n_in,
                              void* d_out, int out_size, void* d_ws, size_t ws_size,
                              hipStream_t stream) {
  const float* x       = (const float*)d_in[0];
  const float* contrib = (const float*)d_in[1];
  const float* W       = (const float*)d_in[2];
  const float* alpha   = (const float*)d_in[3];
  float* out = (float*)d_out;
  char*  wsb = (char*)d_ws;

  float* y             = (float*)(wsb + Y_BOFF);
  float* logits        = (float*)(wsb + L_BOFF);
  float* v             = (float*)(wsb + V_BOFF);
  float* s_part        = (float*)(wsb + SP_BOFF);
  // bT hi/lo alias the s_part region (consumed before s_part first written)
  unsigned short* bThi = (unsigned short*)(wsb + SP_BOFF);
  unsigned short* bTlo = (unsigned short*)(wsb + SP_BOFF + BT_SZ);

  conv_w<<<N_, 256, 0, stream>>>(W, bThi, bTlo);
  gemm_fn<<<M_/64, 512, 0, stream>>>(x, bThi, bTlo, y);

  route_pipe<<<dim3(NCH, B_), 256, 0, stream>>>(y, alpha, contrib, logits, v, s_part, 0);
  squash_k<<<B_*CAPS_, 128, 0, stream>>>(s_part, v);

  for (int it=0; it<3; ++it) {
    route_pipe<<<dim3(NCH, B_), 256, 0, stream>>>(y, alpha, contrib, logits, v, s_part, 1);
    squash_k<<<B_*CAPS_, 128, 0, stream>>>(s_part, (it==2) ? out : v);
  }
}